// Round 8
// baseline (158.320 us; speedup 1.0000x reference)
//
#include <hip/hip_runtime.h>

#define B_ 4096
#define T_ 1024
#define H_ 15

// ===== R4: h-state + Pade[7/6] tanh, SINGLE asm block per step =====
// R3 lesson: splitting the step into two asm blocks (STEPA/STEPB with
// hN,rD threaded through C locals) cost ~30 issue cy/step of register-
// shuffle glue (VALUBusy 63.9% x 214cy = 137 issue vs ~102 counted).
// R4 keeps R3's verified math but emits ONE block per step:
//   - D (denominator) scheduled FIRST after tq2 -> v_rcp issues early;
//   - N, hN, bs computed in the rcp latency shadow;
//   - u = hN*rD closes the block; s_nop 1 = 2 DPP wait states.
//
// Math (verified by R3 pass, absmax 0.0039):
//   a = sum_c w_hh[m][c] h[c] + (b_ih+b_hh)[m] + x_t*w_ih[m]
//   h' = tanh(a) ~= ab*N(t)/D(t), ab = clamp(a,-5,5), t = ab^2
//   N = 135135 + 17325 t + 378 t^2 + t^3
//   D = 135135 + 62370 t + 3150 t^2 + 28 t^3
// Head-fold: lane 15 weights = w_lin, bias = b_lin, wih = 0 -> lane 15's
// 'a' = out[t-1] exactly, retired one step delayed. Lane 15's own h is
// bounded garbage, never consumed (all c=15 weights are 0).
//
// Hazards: same-chain DPP fmac spacing 4 (A/B/C/D round-robin); plain-VALU
// deps >= 2 instrs apart where free (a/med3/tq accept ~2cy each); rcp ->
// u gap = 3 instrs; u -> next block's DPP reads covered by s_nop 1.
#define STEP(XTN, ODST)                                                       \
  do {                                                                        \
    float cA_, cB_, cC_, cD_, t1_, t2_, ab_, tq_, tq2_, nA_, dA_, nB_, dB_,   \
        N_, D_, rD_, hN_;                                                     \
    asm("v_mul_f32_dpp %[cB], %[u], %[w1] row_ror:1 row_mask:0xf bank_mask:0xf\n\t"   \
        "v_mul_f32_dpp %[cC], %[u], %[w2] row_ror:2 row_mask:0xf bank_mask:0xf\n\t"   \
        "v_mul_f32_dpp %[cD], %[u], %[w3] row_ror:3 row_mask:0xf bank_mask:0xf\n\t"   \
        "v_fma_f32 %[cA], %[u], %[w0], %[bs]\n\t"                             \
        "v_fmac_f32_dpp %[cB], %[u], %[w5] row_ror:5 row_mask:0xf bank_mask:0xf\n\t"  \
        "v_fmac_f32_dpp %[cC], %[u], %[w6] row_ror:6 row_mask:0xf bank_mask:0xf\n\t"  \
        "v_fmac_f32_dpp %[cD], %[u], %[w7] row_ror:7 row_mask:0xf bank_mask:0xf\n\t"  \
        "v_fmac_f32_dpp %[cA], %[u], %[w4] row_ror:4 row_mask:0xf bank_mask:0xf\n\t"  \
        "v_fmac_f32_dpp %[cB], %[u], %[w9] row_ror:9 row_mask:0xf bank_mask:0xf\n\t"  \
        "v_fmac_f32_dpp %[cC], %[u], %[w10] row_ror:10 row_mask:0xf bank_mask:0xf\n\t" \
        "v_fmac_f32_dpp %[cD], %[u], %[w11] row_ror:11 row_mask:0xf bank_mask:0xf\n\t" \
        "v_fmac_f32_dpp %[cA], %[u], %[w8] row_ror:8 row_mask:0xf bank_mask:0xf\n\t"  \
        "v_fmac_f32_dpp %[cB], %[u], %[w13] row_ror:13 row_mask:0xf bank_mask:0xf\n\t" \
        "v_fmac_f32_dpp %[cC], %[u], %[w14] row_ror:14 row_mask:0xf bank_mask:0xf\n\t" \
        "v_fmac_f32_dpp %[cD], %[u], %[w15] row_ror:15 row_mask:0xf bank_mask:0xf\n\t" \
        "v_fmac_f32_dpp %[cA], %[u], %[w12] row_ror:12 row_mask:0xf bank_mask:0xf\n\t" \
        "v_add_f32 %[t1], %[cB], %[cC]\n\t"                                   \
        "v_add_f32 %[t2], %[cD], %[cA]\n\t"                                   \
        "v_add_f32 %[a], %[t1], %[t2]\n\t"                                    \
        "v_med3_f32 %[ab], %[a], %[m5], %[p5]\n\t"                            \
        "v_mul_f32 %[tq], %[ab], %[ab]\n\t"                                   \
        "v_fma_f32 %[dA], %[tq], %[k62370], %[kBig]\n\t"                      \
        "v_fma_f32 %[dB], %[tq], %[k28], %[k3150]\n\t"                        \
        "v_mul_f32 %[tq2], %[tq], %[tq]\n\t"                                  \
        "v_fma_f32 %[nA], %[tq], %[k17325], %[kBig]\n\t"                      \
        "v_fma_f32 %[D], %[tq2], %[dB], %[dA]\n\t"                            \
        "v_add_f32 %[nB], %[tq], %[k378]\n\t"                                 \
        "v_rcp_f32 %[rD], %[D]\n\t"                                           \
        "v_fma_f32 %[N], %[tq2], %[nB], %[nA]\n\t"                            \
        "v_mul_f32 %[hN], %[ab], %[N]\n\t"                                    \
        "v_fma_f32 %[bs], %[xtn], %[wih], %[bias]\n\t"                        \
        "v_mul_f32 %[u], %[hN], %[rD]\n\t"                                    \
        "s_nop 1\n\t"                                                         \
        : [u] "+v"(u), [bs] "+v"(bs), [a] "=&v"(ODST),                        \
          [cA] "=&v"(cA_), [cB] "=&v"(cB_), [cC] "=&v"(cC_), [cD] "=&v"(cD_), \
          [t1] "=&v"(t1_), [t2] "=&v"(t2_), [ab] "=&v"(ab_),                  \
          [tq] "=&v"(tq_), [tq2] "=&v"(tq2_), [nA] "=&v"(nA_),                \
          [dA] "=&v"(dA_), [nB] "=&v"(nB_), [dB] "=&v"(dB_), [N] "=&v"(N_),   \
          [D] "=&v"(D_), [rD] "=&v"(rD_), [hN] "=&v"(hN_)                     \
        : [xtn] "v"(XTN), [wih] "v"(wih2), [bias] "v"(bias2),                 \
          [kBig] "v"(kBig), [k17325] "v"(k17325), [k62370] "v"(k62370),       \
          [k378] "v"(k378), [k3150] "v"(k3150), [k28] "v"(k28),               \
          [m5] "v"(m5), [p5] "v"(p5),                                         \
          [w0] "v"(wr[0]), [w1] "v"(wr[1]), [w2] "v"(wr[2]),                  \
          [w3] "v"(wr[3]), [w4] "v"(wr[4]), [w5] "v"(wr[5]),                  \
          [w6] "v"(wr[6]), [w7] "v"(wr[7]), [w8] "v"(wr[8]),                  \
          [w9] "v"(wr[9]), [w10] "v"(wr[10]), [w11] "v"(wr[11]),              \
          [w12] "v"(wr[12]), [w13] "v"(wr[13]), [w14] "v"(wr[14]),            \
          [w15] "v"(wr[15]));                                                 \
  } while (0)

// Pipeline position K (0..31): runs step t+K; XV is x for step t+K+1
// (feeds the in-asm bs prefetch). Lane-15 'a' = out[t+K-1] -> staged at
// (K-1)&3; finished 4-pack stored at K%4==0 (skip the first, garbage,
// retirement); one x buffer refilled per 4 steps (refill-to-use = 28 steps).
#define POS(K, XV)                                                            \
  do {                                                                        \
    float o_;                                                                 \
    STEP(XV, o_);                                                             \
    osta[((K) + 3) & 3] = o_;                                                 \
    if (((K) & 3) == 0) {                                                     \
      if ((K) > 0 || t > 0) {                                                 \
        if (m == 15)                                                          \
          *(float4*)(ob + t + (K) - 4) =                                      \
              make_float4(osta[0], osta[1], osta[2], osta[3]);                \
      }                                                                       \
    }                                                                         \
    if (((K) & 3) == 3) {                                                     \
      int _tn = t + 32 + (((K) >> 2) << 2);                                   \
      if (_tn >= T_) _tn = 0; /* clamped dummy refill near the end */         \
      qq[(K) >> 2] = *(const float4*)(xb + _tn);                              \
    }                                                                         \
  } while (0)

// 16 lanes/batch, 4 batches/wave, 1024 waves = 1 wave/SIMD.
__global__ __attribute__((amdgpu_flat_work_group_size(256, 256),
                          amdgpu_waves_per_eu(1, 1)))
void rnn_tanh_kernel(
    const float* __restrict__ x, const float* __restrict__ w_ih,
    const float* __restrict__ w_hh, const float* __restrict__ b_ih,
    const float* __restrict__ b_hh, const float* __restrict__ w_lin,
    const float* __restrict__ b_lin, float* __restrict__ out) {
  const int tid = threadIdx.x;
  const int m = tid & 15;                      // hidden row (15 = head lane)
  const int b = blockIdx.x * 16 + (tid >> 4);  // batch index

  // Rotation-permuted weights (rot n reads h[(m-n)&15]).
  // Lanes 0..14: recurrence rows (plain). Lane 15: head weights.
  float wr[16];
#pragma unroll
  for (int n = 0; n < 16; ++n) {
    const int c = (m - n) & 15;
    if (m < H_)
      wr[n] = (c < H_) ? w_hh[m * H_ + c] : 0.0f;
    else
      wr[n] = (c < H_) ? w_lin[c] : 0.0f;
  }
  const float wih2  = (m < H_) ? w_ih[m] : 0.0f;
  const float bias2 = (m < H_) ? (b_ih[m] + b_hh[m]) : b_lin[0];

  // Pade[7/6] constants (exact in f32; kept in VGPRs -- VOP3 forbids
  // literals and float values are not inline consts).
  const float kBig = 135135.0f, k17325 = 17325.0f, k62370 = 62370.0f;
  const float k378 = 378.0f, k3150 = 3150.0f, k28 = 28.0f;
  const float m5 = -5.0f, p5 = 5.0f;

  const float* xb = x + (size_t)b * T_;
  float* ob = out + (size_t)b * T_;

  float u = 0.0f;  // h0 = 0 (lane 15's h is never consumed)
  asm("s_nop 1" : "+v"(u));  // guard: >=2 wait states before first DPP read
  float osta[4];             // output staging (constant-indexed -> registers)

  // 8-buffer x software pipeline.
  float4 qq[8];
#pragma unroll
  for (int j = 0; j < 8; ++j) qq[j] = *(const float4*)(xb + 4 * j);

  // bs for step 0 (prefetched pattern: STEP consumes current bs, computes next).
  float bs = fmaf(qq[0].x, wih2, bias2);

  for (int t = 0; t < T_; t += 32) {
    POS(0,  qq[0].y); POS(1,  qq[0].z); POS(2,  qq[0].w); POS(3,  qq[1].x);
    POS(4,  qq[1].y); POS(5,  qq[1].z); POS(6,  qq[1].w); POS(7,  qq[2].x);
    POS(8,  qq[2].y); POS(9,  qq[2].z); POS(10, qq[2].w); POS(11, qq[3].x);
    POS(12, qq[3].y); POS(13, qq[3].z); POS(14, qq[3].w); POS(15, qq[4].x);
    POS(16, qq[4].y); POS(17, qq[4].z); POS(18, qq[4].w); POS(19, qq[5].x);
    POS(20, qq[5].y); POS(21, qq[5].z); POS(22, qq[5].w); POS(23, qq[6].x);
    POS(24, qq[6].y); POS(25, qq[6].z); POS(26, qq[6].w); POS(27, qq[7].x);
    POS(28, qq[7].y); POS(29, qq[7].z); POS(30, qq[7].w); POS(31, qq[0].x);
  }

  // Epilogue: one extra STEP (dummy x feeds only the dead bs prefetch) —
  // its lane-15 'a' reads the final h_{T-1}, producing out[T-1]; complete
  // and store the last 4-pack.
  {
    float o_;
    STEP(0.0f, o_);
    osta[3] = o_;
    if (m == 15)
      *(float4*)(ob + T_ - 4) = make_float4(osta[0], osta[1], osta[2], osta[3]);
  }
}

extern "C" void kernel_launch(void* const* d_in, const int* in_sizes, int n_in,
                              void* d_out, int out_size, void* d_ws, size_t ws_size,
                              hipStream_t stream) {
  (void)in_sizes; (void)n_in; (void)out_size; (void)d_ws; (void)ws_size;
  rnn_tanh_kernel<<<B_ / 16, 256, 0, stream>>>(
      (const float*)d_in[0], (const float*)d_in[1], (const float*)d_in[2],
      (const float*)d_in[3], (const float*)d_in[4], (const float*)d_in[5],
      (const float*)d_in[6], (float*)d_out);
}

// Round 9
// 138.912 us; speedup vs baseline: 1.1397x; 1.1397x over previous
//
#include <hip/hip_runtime.h>

#define B_ 4096
#define T_ 1024
#define H_ 15

// ===== R5: R0's exp-sigmoid math, issue-minimal schedule =====
// Cost model (fits R0/R1/R2/R3/R4 within 3%): EVERY VALU op = 4 cy issue
// (DPP no costlier than plain), trans = 8 cy issue; exposed loop-carried
// chain ~73 cy (combine adds + exp(25) + add + rcp(25) + waits).
//   -> wall = issue + 73.  R0 issue = 100.  This kernel: 97.
// Changes vs R0: 3 MAC chains (A:6 ops seeded with bs, B/C:5) at round-robin
// spacing 3 -> combine is 2 adds (was 3); bs-prefetch fma fills the exp
// wait state (drops one s_nop).
//
// State: u = 1/(exp2(a)+1)  (h = 1-2u, never materialized).
// Head-fold: lane 15 (pad row) carries the output head in its MAC chains:
// wr15[n] = -2*w_lin[(15-n)&15], bias15 = C = b_lin + sum(w_lin) -> lane
// 15's full tree sum 'a' = C - 2*sum(w_lin*u_prev) = out[t-1] (one-step
// delayed retirement). u[15] garbage, never consumed (all c=15 weights 0).
//
// Hazards: same-chain fmac spacing 3 (A/B/C round-robin); exp->consumer
// 1 wait state (filled by bs fma); rcp->plain-read 1 state and
// rcp->DPP-read 2 states covered by s_nop 1 (+1 extra slack: first DPP
// read sits at position 2 of the next block).
#define STEP(XTN, ODST)                                                       \
  do {                                                                        \
    float cA_, cB_, cC_, t1_, e_;                                             \
    asm("v_fma_f32 %[cA], %[u], %[w0], %[bs]\n\t"                             \
        "v_mul_f32_dpp %[cB], %[u], %[w1] row_ror:1 row_mask:0xf bank_mask:0xf\n\t"   \
        "v_mul_f32_dpp %[cC], %[u], %[w2] row_ror:2 row_mask:0xf bank_mask:0xf\n\t"   \
        "v_fmac_f32_dpp %[cA], %[u], %[w3] row_ror:3 row_mask:0xf bank_mask:0xf\n\t"  \
        "v_fmac_f32_dpp %[cB], %[u], %[w4] row_ror:4 row_mask:0xf bank_mask:0xf\n\t"  \
        "v_fmac_f32_dpp %[cC], %[u], %[w5] row_ror:5 row_mask:0xf bank_mask:0xf\n\t"  \
        "v_fmac_f32_dpp %[cA], %[u], %[w6] row_ror:6 row_mask:0xf bank_mask:0xf\n\t"  \
        "v_fmac_f32_dpp %[cB], %[u], %[w7] row_ror:7 row_mask:0xf bank_mask:0xf\n\t"  \
        "v_fmac_f32_dpp %[cC], %[u], %[w8] row_ror:8 row_mask:0xf bank_mask:0xf\n\t"  \
        "v_fmac_f32_dpp %[cA], %[u], %[w9] row_ror:9 row_mask:0xf bank_mask:0xf\n\t"  \
        "v_fmac_f32_dpp %[cB], %[u], %[w10] row_ror:10 row_mask:0xf bank_mask:0xf\n\t" \
        "v_fmac_f32_dpp %[cC], %[u], %[w11] row_ror:11 row_mask:0xf bank_mask:0xf\n\t" \
        "v_fmac_f32_dpp %[cA], %[u], %[w12] row_ror:12 row_mask:0xf bank_mask:0xf\n\t" \
        "v_fmac_f32_dpp %[cB], %[u], %[w13] row_ror:13 row_mask:0xf bank_mask:0xf\n\t" \
        "v_fmac_f32_dpp %[cC], %[u], %[w14] row_ror:14 row_mask:0xf bank_mask:0xf\n\t" \
        "v_fmac_f32_dpp %[cA], %[u], %[w15] row_ror:15 row_mask:0xf bank_mask:0xf\n\t" \
        "v_add_f32 %[t1], %[cB], %[cC]\n\t"                                   \
        "v_add_f32 %[a], %[t1], %[cA]\n\t"                                    \
        "v_exp_f32 %[e], %[a]\n\t"                                            \
        "v_fma_f32 %[bs], %[xtn], %[wih], %[bias]\n\t"                        \
        "v_add_f32 %[e], 1.0, %[e]\n\t"                                       \
        "v_rcp_f32 %[u], %[e]\n\t"                                            \
        "s_nop 1\n\t"                                                         \
        : [u] "+v"(u), [bs] "+v"(bs), [a] "=&v"(ODST),                        \
          [cA] "=&v"(cA_), [cB] "=&v"(cB_), [cC] "=&v"(cC_),                  \
          [t1] "=&v"(t1_), [e] "=&v"(e_)                                      \
        : [xtn] "v"(XTN), [wih] "v"(wih2), [bias] "v"(bias2),                 \
          [w0] "v"(wr[0]), [w1] "v"(wr[1]), [w2] "v"(wr[2]),                  \
          [w3] "v"(wr[3]), [w4] "v"(wr[4]), [w5] "v"(wr[5]),                  \
          [w6] "v"(wr[6]), [w7] "v"(wr[7]), [w8] "v"(wr[8]),                  \
          [w9] "v"(wr[9]), [w10] "v"(wr[10]), [w11] "v"(wr[11]),              \
          [w12] "v"(wr[12]), [w13] "v"(wr[13]), [w14] "v"(wr[14]),            \
          [w15] "v"(wr[15]));                                                 \
  } while (0)

// Pipeline position K (0..31): runs step t+K; XV is x for step t+K+1
// (feeds the in-asm bs prefetch). Lane-15 'a' = out[t+K-1] -> staged at
// (K-1)&3; finished 4-pack stored at K%4==0 (skip the first, garbage,
// retirement); one x buffer refilled per 4 steps (refill-to-use = 28 steps).
#define POS(K, XV)                                                            \
  do {                                                                        \
    float o_;                                                                 \
    STEP(XV, o_);                                                             \
    osta[((K) + 3) & 3] = o_;                                                 \
    if (((K) & 3) == 0) {                                                     \
      if ((K) > 0 || t > 0) {                                                 \
        if (m == 15)                                                          \
          *(float4*)(ob + t + (K) - 4) =                                      \
              make_float4(osta[0], osta[1], osta[2], osta[3]);                \
      }                                                                       \
    }                                                                         \
    if (((K) & 3) == 3) {                                                     \
      int _tn = t + 32 + (((K) >> 2) << 2);                                   \
      if (_tn >= T_) _tn = 0; /* clamped dummy refill near the end */         \
      qq[(K) >> 2] = *(const float4*)(xb + _tn);                              \
    }                                                                         \
  } while (0)

// 16 lanes/batch, 4 batches/wave, 1024 waves = 1 wave/SIMD.
__global__ __attribute__((amdgpu_flat_work_group_size(256, 256),
                          amdgpu_waves_per_eu(1, 1)))
void rnn_tanh_kernel(
    const float* __restrict__ x, const float* __restrict__ w_ih,
    const float* __restrict__ w_hh, const float* __restrict__ b_ih,
    const float* __restrict__ b_hh, const float* __restrict__ w_lin,
    const float* __restrict__ b_lin, float* __restrict__ out) {
  const int tid = threadIdx.x;
  const int m = tid & 15;                      // hidden row (15 = head lane)
  const int b = blockIdx.x * 16 + (tid >> 4);  // batch index

  const float S = 2.8853900817779268f;         // 2*log2(e)

  // out = C - 2*sum(w_lin*u), C = b_lin + sum(w_lin).
  float wsum = b_lin[0];
  for (int j = 0; j < H_; ++j) wsum += w_lin[j];
  const float C = wsum;

  // Rotation-permuted weights (rot n reads u[(m-n)&15]).
  // Lanes 0..14: recurrence rows, scaled by -2S. Lane 15: head weights.
  float wr[16];
#pragma unroll
  for (int n = 0; n < 16; ++n) {
    const int c = (m - n) & 15;
    if (m < H_)
      wr[n] = (c < H_) ? -2.0f * S * w_hh[m * H_ + c] : 0.0f;
    else
      wr[n] = (c < H_) ? -2.0f * w_lin[c] : 0.0f;
  }
  float rowsum = 0.0f;
  if (m < H_)
    for (int j = 0; j < H_; ++j) rowsum += w_hh[m * H_ + j];
  const float wih2  = (m < H_) ? S * w_ih[m] : 0.0f;
  const float bias2 = (m < H_) ? S * (b_ih[m] + b_hh[m] + rowsum) : C;

  const float* xb = x + (size_t)b * T_;
  float* ob = out + (size_t)b * T_;

  float u = 0.5f;  // h=0 -> u=0.5 (lane 15's u is never consumed)
  asm("s_nop 1" : "+v"(u));  // guard: >=2 wait states before first DPP read
  float osta[4];             // output staging (constant-indexed -> registers)

  // 8-buffer x software pipeline.
  float4 qq[8];
#pragma unroll
  for (int j = 0; j < 8; ++j) qq[j] = *(const float4*)(xb + 4 * j);

  // bs for step 0 (prefetched pattern: STEP consumes current bs, computes next).
  float bs = fmaf(qq[0].x, wih2, bias2);

  for (int t = 0; t < T_; t += 32) {
    POS(0,  qq[0].y); POS(1,  qq[0].z); POS(2,  qq[0].w); POS(3,  qq[1].x);
    POS(4,  qq[1].y); POS(5,  qq[1].z); POS(6,  qq[1].w); POS(7,  qq[2].x);
    POS(8,  qq[2].y); POS(9,  qq[2].z); POS(10, qq[2].w); POS(11, qq[3].x);
    POS(12, qq[3].y); POS(13, qq[3].z); POS(14, qq[3].w); POS(15, qq[4].x);
    POS(16, qq[4].y); POS(17, qq[4].z); POS(18, qq[4].w); POS(19, qq[5].x);
    POS(20, qq[5].y); POS(21, qq[5].z); POS(22, qq[5].w); POS(23, qq[6].x);
    POS(24, qq[6].y); POS(25, qq[6].z); POS(26, qq[6].w); POS(27, qq[7].x);
    POS(28, qq[7].y); POS(29, qq[7].z); POS(30, qq[7].w); POS(31, qq[0].x);
  }

  // Epilogue: one extra STEP (dummy x feeds only the dead bs prefetch; lane
  // 15's bs = C regardless of x since wih2=0 there) — its lane-15 'a' reads
  // the final u_{T-1}, producing out[T-1]; complete and store the last 4-pack.
  {
    float o_;
    STEP(0.0f, o_);
    osta[3] = o_;
    if (m == 15)
      *(float4*)(ob + T_ - 4) = make_float4(osta[0], osta[1], osta[2], osta[3]);
  }
}

extern "C" void kernel_launch(void* const* d_in, const int* in_sizes, int n_in,
                              void* d_out, int out_size, void* d_ws, size_t ws_size,
                              hipStream_t stream) {
  (void)in_sizes; (void)n_in; (void)out_size; (void)d_ws; (void)ws_size;
  rnn_tanh_kernel<<<B_ / 16, 256, 0, stream>>>(
      (const float*)d_in[0], (const float*)d_in[1], (const float*)d_in[2],
      (const float*)d_in[3], (const float*)d_in[4], (const float*)d_in[5],
      (const float*)d_in[6], (float*)d_out);
}

// Round 13
// 134.668 us; speedup vs baseline: 1.1756x; 1.0315x over previous
//
#include <hip/hip_runtime.h>

#define B_ 4096
#define T_ 1024
#define H_ 15

// ===== R6: exp-sigmoid, 2-chain MAC, minimal tail =====
// Cost model (fits R0-R5 within 3%): VALU = 4 cy issue, trans = 8 cy issue,
// exposed loop-carried chain ~71 cy.  wall = issue + 71.
//   R5 issue 94.5 (meas).  R6: -4 (one fewer combine add) -2 (s_nop 1->0)
//   -> ~89-91 cy -> dispatch ~68-69.5 us.
// Changes vs R5: 2 MAC chains of 8 (A: rot 0,2,..,14 seeded with bs;
// B: rot 1,3,..,15) at spacing 2 (dep-fmac fwd latency ~4cy < 8cy between
// same-chain ops -- no stall expected); combine = ONE add; tail s_nop 0
// (rcp->plain-read 1 state = s_nop0; rcp->DPP-read 2 states = s_nop0 +
// the plain fma at next block's position 1).
//
// State: u = 1/(exp2(a)+1)  (h = 1-2u, never materialized).
// Head-fold: lane 15 (pad row) carries the output head in its MAC chains:
// wr15[n] = -2*w_lin[(15-n)&15], bias15 = C = b_lin + sum(w_lin) -> lane
// 15's full sum 'a' = C - 2*sum(w_lin*u_prev) = out[t-1] (one-step
// delayed retirement). u[15] garbage, never consumed (all c=15 weights 0).
#define STEP(XTN, ODST)                                                       \
  do {                                                                        \
    float cA_, cB_, e_;                                                       \
    asm("v_fma_f32 %[cA], %[u], %[w0], %[bs]\n\t"                             \
        "v_mul_f32_dpp %[cB], %[u], %[w1] row_ror:1 row_mask:0xf bank_mask:0xf\n\t"   \
        "v_fmac_f32_dpp %[cA], %[u], %[w2] row_ror:2 row_mask:0xf bank_mask:0xf\n\t"  \
        "v_fmac_f32_dpp %[cB], %[u], %[w3] row_ror:3 row_mask:0xf bank_mask:0xf\n\t"  \
        "v_fmac_f32_dpp %[cA], %[u], %[w4] row_ror:4 row_mask:0xf bank_mask:0xf\n\t"  \
        "v_fmac_f32_dpp %[cB], %[u], %[w5] row_ror:5 row_mask:0xf bank_mask:0xf\n\t"  \
        "v_fmac_f32_dpp %[cA], %[u], %[w6] row_ror:6 row_mask:0xf bank_mask:0xf\n\t"  \
        "v_fmac_f32_dpp %[cB], %[u], %[w7] row_ror:7 row_mask:0xf bank_mask:0xf\n\t"  \
        "v_fmac_f32_dpp %[cA], %[u], %[w8] row_ror:8 row_mask:0xf bank_mask:0xf\n\t"  \
        "v_fmac_f32_dpp %[cB], %[u], %[w9] row_ror:9 row_mask:0xf bank_mask:0xf\n\t"  \
        "v_fmac_f32_dpp %[cA], %[u], %[w10] row_ror:10 row_mask:0xf bank_mask:0xf\n\t" \
        "v_fmac_f32_dpp %[cB], %[u], %[w11] row_ror:11 row_mask:0xf bank_mask:0xf\n\t" \
        "v_fmac_f32_dpp %[cA], %[u], %[w12] row_ror:12 row_mask:0xf bank_mask:0xf\n\t" \
        "v_fmac_f32_dpp %[cB], %[u], %[w13] row_ror:13 row_mask:0xf bank_mask:0xf\n\t" \
        "v_fmac_f32_dpp %[cA], %[u], %[w14] row_ror:14 row_mask:0xf bank_mask:0xf\n\t" \
        "v_fmac_f32_dpp %[cB], %[u], %[w15] row_ror:15 row_mask:0xf bank_mask:0xf\n\t" \
        "v_add_f32 %[a], %[cA], %[cB]\n\t"                                    \
        "v_exp_f32 %[e], %[a]\n\t"                                            \
        "v_fma_f32 %[bs], %[xtn], %[wih], %[bias]\n\t"                        \
        "v_add_f32 %[e], 1.0, %[e]\n\t"                                       \
        "v_rcp_f32 %[u], %[e]\n\t"                                            \
        "s_nop 0\n\t"                                                         \
        : [u] "+v"(u), [bs] "+v"(bs), [a] "=&v"(ODST),                        \
          [cA] "=&v"(cA_), [cB] "=&v"(cB_), [e] "=&v"(e_)                     \
        : [xtn] "v"(XTN), [wih] "v"(wih2), [bias] "v"(bias2),                 \
          [w0] "v"(wr[0]), [w1] "v"(wr[1]), [w2] "v"(wr[2]),                  \
          [w3] "v"(wr[3]), [w4] "v"(wr[4]), [w5] "v"(wr[5]),                  \
          [w6] "v"(wr[6]), [w7] "v"(wr[7]), [w8] "v"(wr[8]),                  \
          [w9] "v"(wr[9]), [w10] "v"(wr[10]), [w11] "v"(wr[11]),              \
          [w12] "v"(wr[12]), [w13] "v"(wr[13]), [w14] "v"(wr[14]),            \
          [w15] "v"(wr[15]));                                                 \
  } while (0)

// Pipeline position K (0..31): runs step t+K; XV is x for step t+K+1
// (feeds the in-asm bs prefetch). Lane-15 'a' = out[t+K-1] -> staged at
// (K-1)&3; finished 4-pack stored at K%4==0 (skip the first, garbage,
// retirement); one x buffer refilled per 4 steps (refill-to-use = 28 steps).
#define POS(K, XV)                                                            \
  do {                                                                        \
    float o_;                                                                 \
    STEP(XV, o_);                                                             \
    osta[((K) + 3) & 3] = o_;                                                 \
    if (((K) & 3) == 0) {                                                     \
      if ((K) > 0 || t > 0) {                                                 \
        if (m == 15)                                                          \
          *(float4*)(ob + t + (K) - 4) =                                      \
              make_float4(osta[0], osta[1], osta[2], osta[3]);                \
      }                                                                       \
    }                                                                         \
    if (((K) & 3) == 3) {                                                     \
      int _tn = t + 32 + (((K) >> 2) << 2);                                   \
      if (_tn >= T_) _tn = 0; /* clamped dummy refill near the end */         \
      qq[(K) >> 2] = *(const float4*)(xb + _tn);                              \
    }                                                                         \
  } while (0)

// 16 lanes/batch, 4 batches/wave, 1024 waves = 1 wave/SIMD.
__global__ __attribute__((amdgpu_flat_work_group_size(256, 256),
                          amdgpu_waves_per_eu(1, 1)))
void rnn_tanh_kernel(
    const float* __restrict__ x, const float* __restrict__ w_ih,
    const float* __restrict__ w_hh, const float* __restrict__ b_ih,
    const float* __restrict__ b_hh, const float* __restrict__ w_lin,
    const float* __restrict__ b_lin, float* __restrict__ out) {
  const int tid = threadIdx.x;
  const int m = tid & 15;                      // hidden row (15 = head lane)
  const int b = blockIdx.x * 16 + (tid >> 4);  // batch index

  const float S = 2.8853900817779268f;         // 2*log2(e)

  // out = C - 2*sum(w_lin*u), C = b_lin + sum(w_lin).
  float wsum = b_lin[0];
  for (int j = 0; j < H_; ++j) wsum += w_lin[j];
  const float C = wsum;

  // Rotation-permuted weights (rot n reads u[(m-n)&15]).
  // Lanes 0..14: recurrence rows, scaled by -2S. Lane 15: head weights.
  float wr[16];
#pragma unroll
  for (int n = 0; n < 16; ++n) {
    const int c = (m - n) & 15;
    if (m < H_)
      wr[n] = (c < H_) ? -2.0f * S * w_hh[m * H_ + c] : 0.0f;
    else
      wr[n] = (c < H_) ? -2.0f * w_lin[c] : 0.0f;
  }
  float rowsum = 0.0f;
  if (m < H_)
    for (int j = 0; j < H_; ++j) rowsum += w_hh[m * H_ + j];
  const float wih2  = (m < H_) ? S * w_ih[m] : 0.0f;
  const float bias2 = (m < H_) ? S * (b_ih[m] + b_hh[m] + rowsum) : C;

  const float* xb = x + (size_t)b * T_;
  float* ob = out + (size_t)b * T_;

  float u = 0.5f;  // h=0 -> u=0.5 (lane 15's u is never consumed)
  asm("s_nop 1" : "+v"(u));  // guard: >=2 wait states before first DPP read
  float osta[4];             // output staging (constant-indexed -> registers)

  // 8-buffer x software pipeline.
  float4 qq[8];
#pragma unroll
  for (int j = 0; j < 8; ++j) qq[j] = *(const float4*)(xb + 4 * j);

  // bs for step 0 (prefetched pattern: STEP consumes current bs, computes next).
  float bs = fmaf(qq[0].x, wih2, bias2);

  for (int t = 0; t < T_; t += 32) {
    POS(0,  qq[0].y); POS(1,  qq[0].z); POS(2,  qq[0].w); POS(3,  qq[1].x);
    POS(4,  qq[1].y); POS(5,  qq[1].z); POS(6,  qq[1].w); POS(7,  qq[2].x);
    POS(8,  qq[2].y); POS(9,  qq[2].z); POS(10, qq[2].w); POS(11, qq[3].x);
    POS(12, qq[3].y); POS(13, qq[3].z); POS(14, qq[3].w); POS(15, qq[4].x);
    POS(16, qq[4].y); POS(17, qq[4].z); POS(18, qq[4].w); POS(19, qq[5].x);
    POS(20, qq[5].y); POS(21, qq[5].z); POS(22, qq[5].w); POS(23, qq[6].x);
    POS(24, qq[6].y); POS(25, qq[6].z); POS(26, qq[6].w); POS(27, qq[7].x);
    POS(28, qq[7].y); POS(29, qq[7].z); POS(30, qq[7].w); POS(31, qq[0].x);
  }

  // Epilogue: one extra STEP (dummy x feeds only the dead bs prefetch; lane
  // 15's bs = C regardless of x since wih2=0 there) — its lane-15 'a' reads
  // the final u_{T-1}, producing out[T-1]; complete and store the last 4-pack.
  {
    float o_;
    STEP(0.0f, o_);
    osta[3] = o_;
    if (m == 15)
      *(float4*)(ob + T_ - 4) = make_float4(osta[0], osta[1], osta[2], osta[3]);
  }
}

extern "C" void kernel_launch(void* const* d_in, const int* in_sizes, int n_in,
                              void* d_out, int out_size, void* d_ws, size_t ws_size,
                              hipStream_t stream) {
  (void)in_sizes; (void)n_in; (void)out_size; (void)d_ws; (void)ws_size;
  rnn_tanh_kernel<<<B_ / 16, 256, 0, stream>>>(
      (const float*)d_in[0], (const float*)d_in[1], (const float*)d_in[2],
      (const float*)d_in[3], (const float*)d_in[4], (const float*)d_in[5],
      (const float*)d_in[6], (float*)d_out);
}